// Round 7
// baseline (869.413 us; speedup 1.0000x reference)
//
#include <hip/hip_runtime.h>

// Problem constants
#define B_  4
#define S_  2048
#define E_  1024
#define H_  16
#define DK_ 64
#define M_  (B_*S_)   // 8192

typedef __attribute__((ext_vector_type(8)))  short short8;   // 8 bf16 (4 VGPRs)
typedef __attribute__((ext_vector_type(4)))  float f32x4;
typedef __attribute__((ext_vector_type(16))) float f32x16;   // 32x32 MFMA accumulator

#define QSCALE 0.18033688f   // 0.125 * log2(e): folded into Q so p = exp2(score)

// fp32 -> bf16 round-to-nearest-even
__device__ __forceinline__ unsigned short f2b(float f) {
    union { float f; unsigned u; } v; v.f = f;
    unsigned u = v.u;
    return (unsigned short)((u + 0x7fffu + ((u >> 16) & 1u)) >> 16);
}

// async global->LDS, 16 bytes/lane. LDS dest = wave-uniform base + lane*16.
__device__ __forceinline__ void gload_lds16(const unsigned short* g, unsigned short* l) {
    __builtin_amdgcn_global_load_lds((const __attribute__((address_space(1))) void*)g,
                                     (__attribute__((address_space(3))) void*)l, 16, 0, 0);
}

// One launch for all fp32->bf16 converts: x (M*E) then Wq,Wk,Wv,Wo (E*E each).
#define XN4 (M_*E_/4)
#define WN4 (E_*E_/4)
__global__ __launch_bounds__(256) void cvt_all(
    const float* __restrict__ x,
    const float* __restrict__ w0, const float* __restrict__ w1,
    const float* __restrict__ w2, const float* __restrict__ w3,
    unsigned short* __restrict__ xb, unsigned short* __restrict__ wb,
    unsigned short* __restrict__ wob) {
    int i = blockIdx.x * 256 + threadIdx.x;
    const float* src;
    unsigned short* dst;
    int idx;
    if (i < XN4) { src = x; dst = xb; idx = i; }
    else {
        int j = i - XN4;
        int z = j >> 18;              // / WN4 (2^18)
        idx = j & (WN4 - 1);
        src = (z == 0) ? w0 : (z == 1) ? w1 : (z == 2) ? w2 : w3;
        dst = (z < 3) ? wb + (size_t)z * E_ * E_ : wob;
    }
    float4 f = ((const float4*)src)[idx];
    ushort4 o;
    o.x = f2b(f.x); o.y = f2b(f.y); o.z = f2b(f.z); o.w = f2b(f.w);
    ((ushort4*)dst)[idx] = o;
}

// ---------------------------------------------------------------------------
// 128x128-tile GEMM (r5 structure, reverted from r6 regression): T2 chunk-XOR
// swizzle; double-buffered LDS with stage-early (stage t+1 BEFORE compute t);
// one __syncthreads per K-tile drains vmcnt after a full compute phase.
// ---------------------------------------------------------------------------
union GemmShm {
    struct { unsigned short As0[8192], Bs0[8192], As1[8192], Bs1[8192]; } kl;  // 64 KiB
    unsigned short epi[18432];                                                  // 36 KiB epilogue scratch
};

__device__ __forceinline__ void gemm_stage(
    const unsigned short* Ag, const unsigned short* Bg,   // bases incl. k0 offset
    unsigned short* As, unsigned short* Bs, int w, int srow, int sch) {
    #pragma unroll
    for (int c = 0; c < 4; c++) {
        int ro = (w*32 + c*8 + srow);
        gload_lds16(Ag + (size_t)ro*E_ + sch, As + (w*32 + c*8)*64);
        gload_lds16(Bg + (size_t)ro*E_ + sch, Bs + (w*32 + c*8)*64);
    }
}

__device__ __forceinline__ void gemm_compute(
    const unsigned short* As, const unsigned short* Bs,
    f32x4 (&acc)[4][4], int wm, int wn, int col, int quad, int rsw) {
    #pragma unroll
    for (int kk = 0; kk < 64; kk += 32) {
        short8 a[4], b[4];
        #pragma unroll
        for (int i = 0; i < 4; i++)
            a[i] = *(const short8*)&As[(wm + i*16 + col)*64 + ((((kk>>3) + quad) ^ rsw) * 8)];
        #pragma unroll
        for (int j = 0; j < 4; j++)
            b[j] = *(const short8*)&Bs[(wn + j*16 + col)*64 + ((((kk>>3) + quad) ^ rsw) * 8)];
        __builtin_amdgcn_s_setprio(1);
        #pragma unroll
        for (int i = 0; i < 4; i++)
            #pragma unroll
            for (int j = 0; j < 4; j++)
                acc[i][j] = __builtin_amdgcn_mfma_f32_16x16x32_bf16(a[i], b[j], acc[i][j], 0, 0, 0);
        __builtin_amdgcn_s_setprio(0);
    }
}

__global__ __launch_bounds__(256) void gemm_qkv(
    const unsigned short* __restrict__ xb,   // [M][E]
    const unsigned short* __restrict__ Wb,   // [3][E][E]
    const float* __restrict__ theta,         // [64]
    unsigned short* __restrict__ qb,         // [B*H][S][DK]  (q pre-scaled)
    unsigned short* __restrict__ kb,         // [B*H][S][DK]
    unsigned short* __restrict__ vtb)        // [B*H][DK][S]
{
    __shared__ GemmShm shm;
    const int tid = threadIdx.x;
    const int w = tid >> 6, lane = tid & 63, quad = lane >> 4, col = lane & 15;
    const int wm = (w & 1) * 64, wn = (w >> 1) * 64;
    const int m0 = blockIdx.x * 128, n0 = blockIdx.y * 128, z = blockIdx.z;
    const unsigned short* Wz = Wb + (size_t)z * E_ * E_;
    const int srow = lane >> 3;
    const int sch  = ((lane & 7) ^ srow) * 8;   // pre-swizzled source chunk
    const int rsw  = col & 7;                   // read-side XOR key (row&7)

    const unsigned short* Ag = xb + (size_t)m0 * E_;
    const unsigned short* Bg = Wz + (size_t)n0 * E_;

    f32x4 acc[4][4] = {};
    gemm_stage(Ag, Bg, shm.kl.As0, shm.kl.Bs0, w, srow, sch);
    __syncthreads();
    for (int k0 = 0; k0 < E_; k0 += 128) {
        gemm_stage(Ag + k0 + 64, Bg + k0 + 64, shm.kl.As1, shm.kl.Bs1, w, srow, sch);
        gemm_compute(shm.kl.As0, shm.kl.Bs0, acc, wm, wn, col, quad, rsw);
        __syncthreads();                              // drains vmcnt: buf1 ready
        if (k0 + 128 < E_)
            gemm_stage(Ag + k0 + 128, Bg + k0 + 128, shm.kl.As0, shm.kl.Bs0, w, srow, sch);
        gemm_compute(shm.kl.As1, shm.kl.Bs1, acc, wm, wn, col, quad, rsw);
        __syncthreads();
    }

    unsigned short* ep = shm.epi;
    const int bblk = m0 >> 11;            // batch index (tile never crosses S)
    const int sbase = m0 & (S_-1);

    if (z != 2) {
        const float qs = (z == 0) ? QSCALE : 1.0f;
        // C -> ep[m][n] (stride 144), quad-XOR swizzle on n (16-elt granularity)
        #pragma unroll
        for (int j = 0; j < 4; j++) {
            int nl = wn + j*16 + col;
            float th = theta[(n0 + nl) & 63];
            #pragma unroll
            for (int i = 0; i < 4; i++)
                #pragma unroll
                for (int r = 0; r < 4; r++) {
                    int ml = wm + i*16 + quad*4 + r;
                    int nls = nl ^ (((ml >> 2) & 3) << 4);
                    ep[ml*144 + nls] = f2b(__cosf(acc[i][j][r] + th) * qs);
                }
        }
        __syncthreads();
        unsigned short* dst = (z == 0) ? qb : kb;
        const int h0 = n0 >> 6;
        #pragma unroll
        for (int k = 0; k < 8; k++) {
            int idx = k*256 + tid;
            int chunk = idx & 7, seg = idx >> 3;
            int ml = seg >> 1, hh = seg & 1;
            int ch = chunk ^ (((ml >> 2) & 3) << 1);     // de-swizzle (8-elt chunks)
            int4 val = *(const int4*)&ep[ml*144 + hh*64 + ch*8];
            size_t g = ((size_t)(bblk*H_ + h0 + hh)*S_ + sbase + ml)*DK_ + chunk*8;
            *(int4*)&dst[g] = val;
        }
    } else {
        // V: transpose tile (n-major) -> vtb[bh][d][s] coalesced rows
        #pragma unroll
        for (int j = 0; j < 4; j++) {
            int nl = wn + j*16 + col;
            float th = theta[(n0 + nl) & 63];
            #pragma unroll
            for (int i = 0; i < 4; i++)
                #pragma unroll
                for (int r = 0; r < 4; r++)
                    ep[nl*136 + wm + i*16 + quad*4 + r] = f2b(__cosf(acc[i][j][r] + th));
        }
        __syncthreads();
        int row = tid >> 1, halfm = (tid & 1) * 64;     // 2 threads per n-row
        int n = n0 + row, h = n >> 6, d = n & 63;
        size_t base = ((size_t)(bblk*H_ + h)*DK_ + d)*S_ + sbase + halfm;
        #pragma unroll
        for (int k = 0; k < 8; k++)
            *(int4*)&vtb[base + k*8] = *(const int4*)&ep[row*136 + halfm + k*8];
    }
}

// out = ctx @ Wo.T, fp32 output (same pipelined K-loop)
__global__ __launch_bounds__(256) void gemm_out(
    const unsigned short* __restrict__ ctx,  // [M][E]
    const unsigned short* __restrict__ Wob,  // [E][E]
    float* __restrict__ out)                 // [M][E] fp32
{
    __shared__ GemmShm shm;
    const int tid = threadIdx.x;
    const int w = tid >> 6, lane = tid & 63, quad = lane >> 4, col = lane & 15;
    const int wm = (w & 1) * 64, wn = (w >> 1) * 64;
    const int m0 = blockIdx.x * 128, n0 = blockIdx.y * 128;
    const int srow = lane >> 3;
    const int sch  = ((lane & 7) ^ srow) * 8;
    const int rsw  = col & 7;

    const unsigned short* Ag = ctx + (size_t)m0 * E_;
    const unsigned short* Bg = Wob + (size_t)n0 * E_;

    f32x4 acc[4][4] = {};
    gemm_stage(Ag, Bg, shm.kl.As0, shm.kl.Bs0, w, srow, sch);
    __syncthreads();
    for (int k0 = 0; k0 < E_; k0 += 128) {
        gemm_stage(Ag + k0 + 64, Bg + k0 + 64, shm.kl.As1, shm.kl.Bs1, w, srow, sch);
        gemm_compute(shm.kl.As0, shm.kl.Bs0, acc, wm, wn, col, quad, rsw);
        __syncthreads();
        if (k0 + 128 < E_)
            gemm_stage(Ag + k0 + 128, Bg + k0 + 128, shm.kl.As0, shm.kl.Bs0, w, srow, sch);
        gemm_compute(shm.kl.As1, shm.kl.Bs1, acc, wm, wn, col, quad, rsw);
        __syncthreads();
    }
    #pragma unroll
    for (int j = 0; j < 4; j++) {
        int n = n0 + wn + j*16 + col;
        #pragma unroll
        for (int i = 0; i < 4; i++)
            #pragma unroll
            for (int r = 0; r < 4; r++) {
                int m = m0 + wm + i*16 + quad*4 + r;
                out[(size_t)m*E_ + n] = acc[i][j][r];
            }
    }
}

// ---------------------------------------------------------------------------
// Flash attention, round-10: SPLIT-K wave specialization.
// 512 threads = 8 waves = 4 q-groups x 2 key-halves; all waves share the same
// staged K/V LDS tiles (staging + LDS-read traffic unchanged), but the whole
// problem is now 4096 waves = 4 waves/SIMD (was 2048 = 2/SIMD, grid-limited).
// Each wave handles its key-half's 2 subtiles per 128-key stage; partial
// oacc/lacc combined once at epilogue through LDS (padded stride 49).
// Keeps: 2 q-sets/wave, dbuf LDS + async-STAGE split, permlane32_swap,
// setprio, XCD-bijective swizzle.
// ---------------------------------------------------------------------------
#define LPK 72    // Kt row stride (64 d + 8 pad)
#define LPV 136   // Vt row stride (128 keys + 8 pad)
#define KVB 128   // keys per stage

__global__ __launch_bounds__(512, 4) void flash_attn(
    const unsigned short* __restrict__ qb,   // pre-scaled by QSCALE
    const unsigned short* __restrict__ kb,
    const unsigned short* __restrict__ vtb,
    unsigned short* __restrict__ ctx)        // [M][E] bf16
{
    __shared__ unsigned short Kt[2][KVB*LPK];   // [buf][key][d]   36864 B
    __shared__ unsigned short Vt[2][64*LPV];    // [buf][d][key]   34816 B
    const int tid = threadIdx.x;
    const int w = tid >> 6, lane = tid & 63, col = lane & 31, half = lane >> 5;
    const int qg = w & 3, kh = w >> 2;          // q-group, key-half

    // 512 blocks = 8 q-tiles x 64 heads. f%8 = XCD; XCD x gets heads [8x,8x+8).
    const int f   = blockIdx.y * gridDim.x + blockIdx.x;   // 0..511
    const int swz = (f & 7) * 64 + (f >> 3);               // bijective (512 = 8*64)
    const int q0  = (swz & 7) * 256;
    const int bh  = swz >> 3;

    const unsigned short* kbase = kb  + (size_t)bh * S_ * DK_;
    const unsigned short* vbase = vtb + (size_t)bh * DK_ * S_;

    // Two Q fragment sets: rows q0 + qg*64 + s*32 + col
    short8 qf[2][4];
    {
        const unsigned short* qrow = qb + ((size_t)bh*S_ + q0 + qg*64 + col)*DK_;
        #pragma unroll
        for (int s = 0; s < 2; s++)
            #pragma unroll
            for (int c = 0; c < 4; c++)
                qf[s][c] = *(const short8*)&qrow[(size_t)s*32*DK_ + c*16 + half*8];
    }

    union U8 { unsigned u[4]; short8 s8; };
    U8 ones;
    #pragma unroll
    for (int i = 0; i < 4; i++) ones.u[i] = 0x3F803F80u;   // bf16 1.0 pair

    f32x16 oacc[2][2] = {};   // [set][dt]
    f32x16 lacc[2] = {};      // [set]

    // prologue: stage tile 0 into buf 0 (K: 128x64, V: 64x128), 512 threads
    #pragma unroll
    for (int j = 0; j < 2; j++) {
        int s = tid + j*512;
        int krow = s >> 3, kc8 = (s & 7) * 8;
        int vrow = s >> 4, vc8 = (s & 15) * 8;
        *(int4*)&Kt[0][krow*LPK + kc8] = *(const int4*)&kbase[(size_t)krow*DK_ + kc8];
        *(int4*)&Vt[0][vrow*LPV + vc8] = *(const int4*)&vbase[(size_t)vrow*S_ + vc8];
    }
    __syncthreads();

    for (int it = 0; it < S_/KVB; ++it) {
        const int cur = it & 1, nxt = cur ^ 1;
        const int ktn = it*KVB + KVB;
        int4 rk[2], rv[2];
        if (ktn < S_) {                      // issue next-tile loads EARLY
            #pragma unroll
            for (int j = 0; j < 2; j++) {
                int s = tid + j*512;
                int krow = s >> 3, kc8 = (s & 7) * 8;
                int vrow = s >> 4, vc8 = (s & 15) * 8;
                rk[j] = *(const int4*)&kbase[(size_t)(ktn + krow)*DK_ + kc8];
                rv[j] = *(const int4*)&vbase[(size_t)vrow*S_ + ktn + vc8];
            }
        }

        #pragma unroll
        for (int tt = 0; tt < 2; tt++) {
            const int t = kh*2 + tt;         // this wave's key subtile
            // S^T = K.Q^T over this 32-key subtile, both q-sets share kf
            f32x16 sa0 = {}, sa1 = {};
            __builtin_amdgcn_s_setprio(1);
            #pragma unroll
            for (int c = 0; c < 4; c++) {
                short8 kf = *(const short8*)&Kt[cur][(t*32 + col)*LPK + c*16 + half*8];
                sa0 = __builtin_amdgcn_mfma_f32_32x32x16_bf16(kf, qf[0][c], sa0, 0, 0, 0);
                sa1 = __builtin_amdgcn_mfma_f32_32x32x16_bf16(kf, qf[1][c], sa1, 0, 0, 0);
            }
            __builtin_amdgcn_s_setprio(0);
            // p = exp2(score); pack pairs via v_perm (hi-16 truncation)
            unsigned pk[2][4][2];
            #pragma unroll
            for (int rg = 0; rg < 4; rg++) {
                float a0 = __builtin_amdgcn_exp2f(sa0[rg*4+0]);
                float a1 = __builtin_amdgcn_exp2f(sa0[rg*4+1]);
                float a2 = __builtin_amdgcn_exp2f(sa0[rg*4+2]);
                float a3 = __builtin_amdgcn_exp2f(sa0[rg*4+3]);
                pk[0][rg][0] = __builtin_amdgcn_perm(__float_as_uint(a1), __float_as_uint(a0), 0x07060302u);
                pk[0][rg][1] = __builtin_amdgcn_perm(__float_as_uint(a3), __float_as_uint(a2), 0x07060302u);
                float b0 = __builtin_amdgcn_exp2f(sa1[rg*4+0]);
                float b1 = __builtin_amdgcn_exp2f(sa1[rg*4+1]);
                float b2 = __builtin_amdgcn_exp2f(sa1[rg*4+2]);
                float b3 = __builtin_amdgcn_exp2f(sa1[rg*4+3]);
                pk[1][rg][0] = __builtin_amdgcn_perm(__float_as_uint(b1), __float_as_uint(b0), 0x07060302u);
                pk[1][rg][1] = __builtin_amdgcn_perm(__float_as_uint(b3), __float_as_uint(b2), 0x07060302u);
            }
            // PV + l over the two 16-key chunks; vf shared across q-sets
            #pragma unroll
            for (int kc = 0; kc < 2; kc++) {
                const int lo = 2*kc, hi = 2*kc + 1;
                U8 pa[2];
                #pragma unroll
                for (int s = 0; s < 2; s++) {
                    auto s0 = __builtin_amdgcn_permlane32_swap((int)pk[s][lo][0], (int)pk[s][hi][0], false, false);
                    auto s1 = __builtin_amdgcn_permlane32_swap((int)pk[s][lo][1], (int)pk[s][hi][1], false, false);
                    pa[s].u[0] = (unsigned)s0[0];
                    pa[s].u[1] = (unsigned)s1[0];
                    pa[s].u[2] = (unsigned)s0[1];
                    pa[s].u[3] = (unsigned)s1[1];
                }
                __builtin_amdgcn_s_setprio(1);
                lacc[0] = __builtin_amdgcn_mfma_f32_32x32x16_bf16(pa[0].s8, ones.s8, lacc[0], 0, 0, 0);
                lacc[1] = __builtin_amdgcn_mfma_f32_32x32x16_bf16(pa[1].s8, ones.s8, lacc[1], 0, 0, 0);
                #pragma unroll
                for (int dt = 0; dt < 2; dt++) {
                    short8 vf = *(const short8*)&Vt[cur][(dt*32 + col)*LPV + t*32 + kc*16 + half*8];
                    oacc[0][dt] = __builtin_amdgcn_mfma_f32_32x32x16_bf16(pa[0].s8, vf, oacc[0][dt], 0, 0, 0);
                    oacc[1][dt] = __builtin_amdgcn_mfma_f32_32x32x16_bf16(pa[1].s8, vf, oacc[1][dt], 0, 0, 0);
                }
                __builtin_amdgcn_s_setprio(0);
            }
        }

        if (ktn < S_) {                      // write next tile LATE (vmcnt here)
            #pragma unroll
            for (int j = 0; j < 2; j++) {
                int s = tid + j*512;
                int krow = s >> 3, kc8 = (s & 7) * 8;
                int vrow = s >> 4, vc8 = (s & 15) * 8;
                *(int4*)&Kt[nxt][krow*LPK + kc8] = rk[j];
                *(int4*)&Vt[nxt][vrow*LPV + vc8] = rv[j];
            }
        }
        __syncthreads();
    }

    // ---- split-K combine: high waves (kh=1) hand partials to low waves ----
    float* fs = (float*)&Kt[0][0];          // 4*64*49*4 B = 50176 <= 73728 B
    #pragma unroll
    for (int s = 0; s < 2; s++) {
        __syncthreads();
        if (kh == 1) {
            float* p = fs + ((size_t)qg*64 + lane)*49;
            #pragma unroll
            for (int dt = 0; dt < 2; dt++)
                #pragma unroll
                for (int r = 0; r < 16; r++) p[dt*16 + r] = oacc[s][dt][r];
            #pragma unroll
            for (int r = 0; r < 16; r++) p[32 + r] = lacc[s][r];
        }
        __syncthreads();
        if (kh == 0) {
            const float* p = fs + ((size_t)qg*64 + lane)*49;
            #pragma unroll
            for (int dt = 0; dt < 2; dt++)
                #pragma unroll
                for (int r = 0; r < 16; r++) oacc[s][dt][r] += p[dt*16 + r];
            #pragma unroll
            for (int r = 0; r < 16; r++) lacc[s][r] += p[32 + r];
        }
    }

    // epilogue (low waves only): lacc rows match oacc rows (row = rr+8*rg+4*half)
    if (kh == 0) {
        const int b = bh >> 4, h = bh & 15;
        #pragma unroll
        for (int s = 0; s < 2; s++)
            #pragma unroll
            for (int rg = 0; rg < 4; rg++)
                #pragma unroll
                for (int rr = 0; rr < 4; rr++) {
                    int row = rr + rg*8 + half*4;
                    float inv = 1.0f / lacc[s][rg*4 + rr];
                    int sq = q0 + qg*64 + s*32 + row;
                    size_t rowoff = ((size_t)(b*S_ + sq))*E_ + h*64;
                    #pragma unroll
                    for (int dt = 0; dt < 2; dt++)
                        ctx[rowoff + dt*32 + col] = f2b(oacc[s][dt][rg*4 + rr] * inv);
                }
    }
}

extern "C" void kernel_launch(void* const* d_in, const int* in_sizes, int n_in,
                              void* d_out, int out_size, void* d_ws, size_t ws_size,
                              hipStream_t stream) {
    (void)in_sizes; (void)n_in; (void)out_size; (void)ws_size;
    const float* x     = (const float*)d_in[0];
    const float* Wq    = (const float*)d_in[1];
    const float* Wk    = (const float*)d_in[2];
    const float* Wv    = (const float*)d_in[3];
    const float* Wo    = (const float*)d_in[4];
    const float* theta = (const float*)d_in[5];
    float* out = (float*)d_out;

    unsigned short* ws  = (unsigned short*)d_ws;
    unsigned short* xb  = ws;                                    // M*E
    unsigned short* Wb  = xb  + (size_t)M_*E_;                   // 3*E*E
    unsigned short* Wob = Wb  + (size_t)3*E_*E_;                 // E*E
    unsigned short* qb  = Wob + (size_t)E_*E_;
    unsigned short* kb  = qb  + (size_t)B_*H_*S_*DK_;
    unsigned short* vtb = kb  + (size_t)B_*H_*S_*DK_;
    unsigned short* ctx = xb;                                    // alias (xb dead after gemm_qkv)

    cvt_all<<<(XN4 + 4*WN4)/256, 256, 0, stream>>>(x, Wq, Wk, Wv, Wo, xb, Wb, Wob);

    gemm_qkv<<<dim3(M_/128, E_/128, 3), 256, 0, stream>>>(xb, Wb, theta, qb, kb, vtb);
    flash_attn<<<dim3(S_/256, B_*H_), 512, 0, stream>>>(qb, kb, vtb, ctx);
    gemm_out<<<dim3(M_/128, E_/128), 256, 0, stream>>>(ctx, Wob, out);
}

// Round 8
// 251.466 us; speedup vs baseline: 3.4574x; 3.4574x over previous
//
#include <hip/hip_runtime.h>

// Problem constants
#define B_  4
#define S_  2048
#define E_  1024
#define H_  16
#define DK_ 64
#define M_  (B_*S_)   // 8192

typedef __attribute__((ext_vector_type(8)))  short short8;   // 8 bf16 (4 VGPRs)
typedef __attribute__((ext_vector_type(4)))  float f32x4;
typedef __attribute__((ext_vector_type(16))) float f32x16;   // 32x32 MFMA accumulator

#define QSCALE 0.18033688f   // 0.125 * log2(e): folded into Q so p = exp2(score)

// fp32 -> bf16 round-to-nearest-even
__device__ __forceinline__ unsigned short f2b(float f) {
    union { float f; unsigned u; } v; v.f = f;
    unsigned u = v.u;
    return (unsigned short)((u + 0x7fffu + ((u >> 16) & 1u)) >> 16);
}

// async global->LDS, 16 bytes/lane. LDS dest = wave-uniform base + lane*16.
__device__ __forceinline__ void gload_lds16(const unsigned short* g, unsigned short* l) {
    __builtin_amdgcn_global_load_lds((const __attribute__((address_space(1))) void*)g,
                                     (__attribute__((address_space(3))) void*)l, 16, 0, 0);
}

// One launch for all fp32->bf16 converts: x (M*E) then Wq,Wk,Wv,Wo (E*E each).
#define XN4 (M_*E_/4)
#define WN4 (E_*E_/4)
__global__ __launch_bounds__(256) void cvt_all(
    const float* __restrict__ x,
    const float* __restrict__ w0, const float* __restrict__ w1,
    const float* __restrict__ w2, const float* __restrict__ w3,
    unsigned short* __restrict__ xb, unsigned short* __restrict__ wb,
    unsigned short* __restrict__ wob) {
    int i = blockIdx.x * 256 + threadIdx.x;
    const float* src;
    unsigned short* dst;
    int idx;
    if (i < XN4) { src = x; dst = xb; idx = i; }
    else {
        int j = i - XN4;
        int z = j >> 18;              // / WN4 (2^18)
        idx = j & (WN4 - 1);
        src = (z == 0) ? w0 : (z == 1) ? w1 : (z == 2) ? w2 : w3;
        dst = (z < 3) ? wb + (size_t)z * E_ * E_ : wob;
    }
    float4 f = ((const float4*)src)[idx];
    ushort4 o;
    o.x = f2b(f.x); o.y = f2b(f.y); o.z = f2b(f.z); o.w = f2b(f.w);
    ((ushort4*)dst)[idx] = o;
}

// ---------------------------------------------------------------------------
// GEMM, round-11: BM=256 BN=128 BK=64, 512 threads/8 waves (wave tile 64x64),
// THREE LDS buffers with counted vmcnt(6): stage tile t+2 while computing
// tile t; boundary wait covers loads issued a full tile earlier (never drains
// in-flight prefetch to 0 in the main loop) -- the T4 discipline r6 missed.
// T2 chunk-XOR swizzle and epilogues unchanged (r6-verified mappings).
// ---------------------------------------------------------------------------
#define NT 16   // K-tiles = E_/64

union GemmShm3 {
    struct { unsigned short A[3][256*64]; unsigned short B[3][128*64]; } kl;  // 147456 B
    unsigned short ep[49152];    // epilogue scratch (96 KiB, aliases kl)
};

// 6 gloads per wave: A rows w*32..+32 (4), B rows w*16..+16 (2)
__device__ __forceinline__ void stage6(const unsigned short* Ag, const unsigned short* Bg,
                                       unsigned short* As, unsigned short* Bs,
                                       int w, int srow, int sch) {
    #pragma unroll
    for (int c = 0; c < 4; c++)
        gload_lds16(Ag + (size_t)(w*32 + c*8 + srow)*E_ + sch, As + (w*32 + c*8)*64);
    #pragma unroll
    for (int c = 0; c < 2; c++)
        gload_lds16(Bg + (size_t)(w*16 + c*8 + srow)*E_ + sch, Bs + (w*16 + c*8)*64);
}

__device__ __forceinline__ void gemm_compute(
    const unsigned short* As, const unsigned short* Bs,
    f32x4 (&acc)[4][4], int wm, int wn, int col, int quad, int rsw) {
    #pragma unroll
    for (int kk = 0; kk < 64; kk += 32) {
        short8 a[4], b[4];
        #pragma unroll
        for (int i = 0; i < 4; i++)
            a[i] = *(const short8*)&As[(wm + i*16 + col)*64 + ((((kk>>3) + quad) ^ rsw) * 8)];
        #pragma unroll
        for (int j = 0; j < 4; j++)
            b[j] = *(const short8*)&Bs[(wn + j*16 + col)*64 + ((((kk>>3) + quad) ^ rsw) * 8)];
        __builtin_amdgcn_s_setprio(1);
        #pragma unroll
        for (int i = 0; i < 4; i++)
            #pragma unroll
            for (int j = 0; j < 4; j++)
                acc[i][j] = __builtin_amdgcn_mfma_f32_16x16x32_bf16(a[i], b[j], acc[i][j], 0, 0, 0);
        __builtin_amdgcn_s_setprio(0);
    }
}

__device__ __forceinline__ void kloop3(const unsigned short* Ag, const unsigned short* Bg,
                                       GemmShm3& shm, f32x4 (&acc)[4][4], int w, int lane) {
    const int quad = lane >> 4, col = lane & 15;
    const int srow = lane >> 3;
    const int sch  = ((lane & 7) ^ srow) * 8;   // pre-swizzled source chunk
    const int rsw  = col & 7;                   // read-side XOR key
    const int wm = (w >> 1) * 64, wn = (w & 1) * 64;

    unsigned short *A0 = shm.kl.A[0], *A1 = shm.kl.A[1], *A2 = shm.kl.A[2];
    unsigned short *B0 = shm.kl.B[0], *B1 = shm.kl.B[1], *B2 = shm.kl.B[2];

    // prologue: stage tiles 0 and 1; wait tile 0 only (tile 1's 6 stay in flight)
    stage6(Ag,      Bg,      A0, B0, w, srow, sch);
    stage6(Ag + 64, Bg + 64, A1, B1, w, srow, sch);
    asm volatile("s_waitcnt vmcnt(6)" ::: "memory");
    __builtin_amdgcn_s_barrier();
    __builtin_amdgcn_sched_barrier(0);

    for (int t = 0; t < NT; ++t) {
        // issue tile t+2 into the buffer freed at the end of iter t-1
        if (t + 2 < NT)
            stage6(Ag + (t+2)*64, Bg + (t+2)*64, A2, B2, w, srow, sch);
        __builtin_amdgcn_sched_barrier(0);     // stage-issue stays above compute

        gemm_compute(A0, B0, acc, wm, wn, col, quad, rsw);

        // counted boundary wait: tile t+1's 6 loads are a full tile old ->
        // nearly free; tile t+2's 6 remain in flight (never drain to 0)
        if (t + 2 < NT) asm volatile("s_waitcnt vmcnt(6)" ::: "memory");
        else            asm volatile("s_waitcnt vmcnt(0)" ::: "memory");
        __builtin_amdgcn_s_barrier();
        __builtin_amdgcn_sched_barrier(0);     // no ds_read hoist above barrier

        unsigned short* tA = A0; A0 = A1; A1 = A2; A2 = tA;
        unsigned short* tB = B0; B0 = B1; B1 = B2; B2 = tB;
    }
}

__global__ __launch_bounds__(512, 2) void gemm_qkv(
    const unsigned short* __restrict__ xb,   // [M][E]
    const unsigned short* __restrict__ Wb,   // [3][E][E]
    const float* __restrict__ theta,         // [64]
    unsigned short* __restrict__ qb,         // [B*H][S][DK]  (q pre-scaled)
    unsigned short* __restrict__ kb,         // [B*H][S][DK]
    unsigned short* __restrict__ vtb)        // [B*H][DK][S]
{
    __shared__ GemmShm3 shm;
    const int tid = threadIdx.x;
    const int w = tid >> 6, lane = tid & 63, quad = lane >> 4, col = lane & 15;
    const int wm = (w >> 1) * 64, wn = (w & 1) * 64;

    // T1 XCD swizzle: each XCD owns 4 m-panels; z slowest within XCD.
    const int f = blockIdx.x;                 // 0..767
    const int xcd = f & 7, idx = f >> 3;      // idx 0..95
    const int m0 = (xcd*4 + (idx & 3)) * 256;
    const int nz = idx >> 2;                  // 0..23
    const int n0 = (nz & 7) * 128;
    const int z  = nz >> 3;

    const unsigned short* Ag = xb + (size_t)m0 * E_;
    const unsigned short* Bg = Wb + (size_t)z * E_ * E_ + (size_t)n0 * E_;

    f32x4 acc[4][4] = {};
    kloop3(Ag, Bg, shm, acc, w, lane);

    unsigned short* ep = shm.ep;
    const int bblk = m0 >> 11;            // batch index (tile never crosses S)
    const int sbase = m0 & (S_-1);

    if (z != 2) {
        const float qs = (z == 0) ? QSCALE : 1.0f;
        // C -> ep[m][n] (stride 144), quad-XOR swizzle on n (16-elt granularity)
        #pragma unroll
        for (int j = 0; j < 4; j++) {
            int nl = wn + j*16 + col;
            float th = theta[(n0 + nl) & 63];
            #pragma unroll
            for (int i = 0; i < 4; i++)
                #pragma unroll
                for (int r = 0; r < 4; r++) {
                    int ml = wm + i*16 + quad*4 + r;
                    int nls = nl ^ (((ml >> 2) & 3) << 4);
                    ep[ml*144 + nls] = f2b(__cosf(acc[i][j][r] + th) * qs);
                }
        }
        __syncthreads();
        unsigned short* dst = (z == 0) ? qb : kb;
        const int h0 = n0 >> 6;
        #pragma unroll
        for (int k = 0; k < 8; k++) {
            int idx2 = k*512 + tid;
            int chunk = idx2 & 7, seg = idx2 >> 3;       // seg 0..511
            int ml = seg >> 1, hh = seg & 1;             // ml 0..255
            int ch = chunk ^ (((ml >> 2) & 3) << 1);     // de-swizzle (8-elt chunks)
            int4 val = *(const int4*)&ep[ml*144 + hh*64 + ch*8];
            size_t g = ((size_t)(bblk*H_ + h0 + hh)*S_ + sbase + ml)*DK_ + chunk*8;
            *(int4*)&dst[g] = val;
        }
    } else {
        // V: transpose tile (n-major) -> vtb[bh][d][s] coalesced rows
        #pragma unroll
        for (int j = 0; j < 4; j++) {
            int nl = wn + j*16 + col;
            float th = theta[(n0 + nl) & 63];
            #pragma unroll
            for (int i = 0; i < 4; i++)
                #pragma unroll
                for (int r = 0; r < 4; r++)
                    ep[nl*264 + wm + i*16 + quad*4 + r] = f2b(__cosf(acc[i][j][r] + th));
        }
        __syncthreads();
        int row = tid >> 2, halfm = (tid & 3) * 64;     // 4 threads per n-row
        int n = n0 + row, h = n >> 6, d = n & 63;
        size_t base = ((size_t)(bblk*H_ + h)*DK_ + d)*S_ + sbase + halfm;
        #pragma unroll
        for (int k = 0; k < 8; k++)
            *(int4*)&vtb[base + k*8] = *(const int4*)&ep[row*264 + halfm + k*8];
    }
}

// out = ctx @ Wo.T, fp32 output (same counted-vmcnt K-loop)
__global__ __launch_bounds__(512, 2) void gemm_out(
    const unsigned short* __restrict__ ctx,  // [M][E]
    const unsigned short* __restrict__ Wob,  // [E][E]
    float* __restrict__ out)                 // [M][E] fp32
{
    __shared__ GemmShm3 shm;
    const int tid = threadIdx.x;
    const int w = tid >> 6, lane = tid & 63, quad = lane >> 4, col = lane & 15;
    const int wm = (w >> 1) * 64, wn = (w & 1) * 64;

    const int f = blockIdx.x;                 // 0..255
    const int xcd = f & 7, idx = f >> 3;      // idx 0..31
    const int m0 = (xcd*4 + (idx & 3)) * 256;
    const int n0 = (idx >> 2) * 128;

    const unsigned short* Ag = ctx + (size_t)m0 * E_;
    const unsigned short* Bg = Wob + (size_t)n0 * E_;

    f32x4 acc[4][4] = {};
    kloop3(Ag, Bg, shm, acc, w, lane);

    #pragma unroll
    for (int j = 0; j < 4; j++) {
        int n = n0 + wn + j*16 + col;
        #pragma unroll
        for (int i = 0; i < 4; i++)
            #pragma unroll
            for (int r = 0; r < 4; r++) {
                int m = m0 + wm + i*16 + quad*4 + r;
                out[(size_t)m*E_ + n] = acc[i][j][r];
            }
    }
}

// ---------------------------------------------------------------------------
// Flash attention (r5/round-8 structure, reverted from r7 spill): KVBLK=128,
// 256 threads, 2 q-sets/wave, dbuf LDS + async-STAGE split, permlane32_swap,
// setprio, XCD-bijective swizzle.
// ---------------------------------------------------------------------------
#define LPK 72    // Kt row stride (64 d + 8 pad)
#define LPV 136   // Vt row stride (128 keys + 8 pad)
#define KVB 128   // keys per stage

__global__ __launch_bounds__(256, 2) void flash_attn(
    const unsigned short* __restrict__ qb,   // pre-scaled by QSCALE
    const unsigned short* __restrict__ kb,
    const unsigned short* __restrict__ vtb,
    unsigned short* __restrict__ ctx)        // [M][E] bf16
{
    __shared__ unsigned short Kt[2][KVB*LPK];   // [buf][key][d]   36864 B
    __shared__ unsigned short Vt[2][64*LPV];    // [buf][d][key]   34816 B
    const int tid = threadIdx.x;
    const int w = tid >> 6, lane = tid & 63, col = lane & 31, half = lane >> 5;

    // 512 blocks = 8 q-tiles x 64 heads. f%8 = XCD; XCD x gets heads [8x,8x+8).
    const int f   = blockIdx.y * gridDim.x + blockIdx.x;   // 0..511
    const int swz = (f & 7) * 64 + (f >> 3);               // bijective (512 = 8*64)
    const int q0  = (swz & 7) * 256;
    const int bh  = swz >> 3;

    const unsigned short* kbase = kb  + (size_t)bh * S_ * DK_;
    const unsigned short* vbase = vtb + (size_t)bh * DK_ * S_;

    // Two Q fragment sets: rows q0 + w*64 + s*32 + col
    short8 qf[2][4];
    {
        const unsigned short* qrow = qb + ((size_t)bh*S_ + q0 + w*64 + col)*DK_;
        #pragma unroll
        for (int s = 0; s < 2; s++)
            #pragma unroll
            for (int c = 0; c < 4; c++)
                qf[s][c] = *(const short8*)&qrow[(size_t)s*32*DK_ + c*16 + half*8];
    }

    union U8 { unsigned u[4]; short8 s8; };
    U8 ones;
    #pragma unroll
    for (int i = 0; i < 4; i++) ones.u[i] = 0x3F803F80u;   // bf16 1.0 pair

    f32x16 oacc[2][2] = {};   // [set][dt]
    f32x16 lacc[2] = {};      // [set]

    // prologue: stage tile 0 into buf 0 (K: 128x64, V: 64x128)
    #pragma unroll
    for (int j = 0; j < 4; j++) {
        int s = tid + j*256;
        int krow = s >> 3, kc8 = (s & 7) * 8;
        int vrow = s >> 4, vc8 = (s & 15) * 8;
        *(int4*)&Kt[0][krow*LPK + kc8] = *(const int4*)&kbase[(size_t)krow*DK_ + kc8];
        *(int4*)&Vt[0][vrow*LPV + vc8] = *(const int4*)&vbase[(size_t)vrow*S_ + vc8];
    }
    __syncthreads();

    for (int it = 0; it < S_/KVB; ++it) {
        const int cur = it & 1, nxt = cur ^ 1;
        const int ktn = it*KVB + KVB;
        int4 rk[4], rv[4];
        if (ktn < S_) {                      // issue next-tile loads EARLY
            #pragma unroll
            for (int j = 0; j < 4; j++) {
                int s = tid + j*256;
                int krow = s >> 3, kc8 = (s & 7) * 8;
                int vrow = s >> 4, vc8 = (s & 15) * 8;
                rk[j] = *(const int4*)&kbase[(size_t)(ktn + krow)*DK_ + kc8];
                rv[j] = *(const int4*)&vbase[(size_t)vrow*S_ + ktn + vc8];
            }
        }

        #pragma unroll
        for (int t = 0; t < 4; t++) {
            // S^T = K.Q^T over this 32-key subtile, both q-sets share kf
            f32x16 sa0 = {}, sa1 = {};
            __builtin_amdgcn_s_setprio(1);
            #pragma unroll
            for (int c = 0; c < 4; c++) {
                short8 kf = *(const short8*)&Kt[cur][(t*32 + col)*LPK + c*16 + half*8];
                sa0 = __builtin_amdgcn_mfma_f32_32x32x16_bf16(kf, qf[0][c], sa0, 0, 0, 0);
                sa1 = __builtin_amdgcn_mfma_f32_32x32x16_bf16(kf, qf[1][c], sa1, 0, 0, 0);
            }
            __builtin_amdgcn_s_setprio(0);
            // p = exp2(score); pack pairs via v_perm (hi-16 truncation)
            unsigned pk[2][4][2];
            #pragma unroll
            for (int rg = 0; rg < 4; rg++) {
                float a0 = __builtin_amdgcn_exp2f(sa0[rg*4+0]);
                float a1 = __builtin_amdgcn_exp2f(sa0[rg*4+1]);
                float a2 = __builtin_amdgcn_exp2f(sa0[rg*4+2]);
                float a3 = __builtin_amdgcn_exp2f(sa0[rg*4+3]);
                pk[0][rg][0] = __builtin_amdgcn_perm(__float_as_uint(a1), __float_as_uint(a0), 0x07060302u);
                pk[0][rg][1] = __builtin_amdgcn_perm(__float_as_uint(a3), __float_as_uint(a2), 0x07060302u);
                float b0 = __builtin_amdgcn_exp2f(sa1[rg*4+0]);
                float b1 = __builtin_amdgcn_exp2f(sa1[rg*4+1]);
                float b2 = __builtin_amdgcn_exp2f(sa1[rg*4+2]);
                float b3 = __builtin_amdgcn_exp2f(sa1[rg*4+3]);
                pk[1][rg][0] = __builtin_amdgcn_perm(__float_as_uint(b1), __float_as_uint(b0), 0x07060302u);
                pk[1][rg][1] = __builtin_amdgcn_perm(__float_as_uint(b3), __float_as_uint(b2), 0x07060302u);
            }
            // PV + l over the two 16-key chunks; vf shared across q-sets
            #pragma unroll
            for (int kc = 0; kc < 2; kc++) {
                const int lo = 2*kc, hi = 2*kc + 1;
                U8 pa[2];
                #pragma unroll
                for (int s = 0; s < 2; s++) {
                    auto s0 = __builtin_amdgcn_permlane32_swap((int)pk[s][lo][0], (int)pk[s][hi][0], false, false);
                    auto s1 = __builtin_amdgcn_permlane32_swap((int)pk[s][lo][1], (int)pk[s][hi][1], false, false);
                    pa[s].u[0] = (unsigned)s0[0];
                    pa[s].u[1] = (unsigned)s1[0];
                    pa[s].u[2] = (unsigned)s0[1];
                    pa[s].u[3] = (unsigned)s1[1];
                }
                __builtin_amdgcn_s_setprio(1);
                lacc[0] = __builtin_amdgcn_mfma_f32_32x32x16_bf16(pa[0].s8, ones.s8, lacc[0], 0, 0, 0);
                lacc[1] = __builtin_amdgcn_mfma_f32_32x32x16_bf16(pa[1].s8, ones.s8, lacc[1], 0, 0, 0);
                #pragma unroll
                for (int dt = 0; dt < 2; dt++) {
                    short8 vf = *(const short8*)&Vt[cur][(dt*32 + col)*LPV + t*32 + kc*16 + half*8];
                    oacc[0][dt] = __builtin_amdgcn_mfma_f32_32x32x16_bf16(pa[0].s8, vf, oacc[0][dt], 0, 0, 0);
                    oacc[1][dt] = __builtin_amdgcn_mfma_f32_32x32x16_bf16(pa[1].s8, vf, oacc[1][dt], 0, 0, 0);
                }
                __builtin_amdgcn_s_setprio(0);
            }
        }

        if (ktn < S_) {                      // write next tile LATE (vmcnt here)
            #pragma unroll
            for (int j = 0; j < 4; j++) {
                int s = tid + j*256;
                int krow = s >> 3, kc8 = (s & 7) * 8;
                int vrow = s >> 4, vc8 = (s & 15) * 8;
                *(int4*)&Kt[nxt][krow*LPK + kc8] = rk[j];
                *(int4*)&Vt[nxt][vrow*LPV + vc8] = rv[j];
            }
        }
        __syncthreads();
    }

    // epilogue: lacc rows match oacc rows exactly (C row = rr + 8*rg + 4*half)
    const int b = bh >> 4, h = bh & 15;
    #pragma unroll
    for (int s = 0; s < 2; s++)
        #pragma unroll
        for (int rg = 0; rg < 4; rg++)
            #pragma unroll
            for (int rr = 0; rr < 4; rr++) {
                int row = rr + rg*8 + half*4;
                float inv = 1.0f / lacc[s][rg*4 + rr];
                int sq = q0 + w*64 + s*32 + row;
                size_t rowoff = ((size_t)(b*S_ + sq))*E_ + h*64;
                #pragma unroll
                for (int dt = 0; dt < 2; dt++)
                    ctx[rowoff + dt*32 + col] = f2b(oacc[s][dt][rg*4 + rr] * inv);
            }
}

extern "C" void kernel_launch(void* const* d_in, const int* in_sizes, int n_in,
                              void* d_out, int out_size, void* d_ws, size_t ws_size,
                              hipStream_t stream) {
    (void)in_sizes; (void)n_in; (void)out_size; (void)ws_size;
    const float* x     = (const float*)d_in[0];
    const float* Wq    = (const float*)d_in[1];
    const float* Wk    = (const float*)d_in[2];
    const float* Wv    = (const float*)d_in[3];
    const float* Wo    = (const float*)d_in[4];
    const float* theta = (const float*)d_in[5];
    float* out = (float*)d_out;

    unsigned short* ws  = (unsigned short*)d_ws;
    unsigned short* xb  = ws;                                    // M*E
    unsigned short* Wb  = xb  + (size_t)M_*E_;                   // 3*E*E
    unsigned short* Wob = Wb  + (size_t)3*E_*E_;                 // E*E
    unsigned short* qb  = Wob + (size_t)E_*E_;
    unsigned short* kb  = qb  + (size_t)B_*H_*S_*DK_;
    unsigned short* vtb = kb  + (size_t)B_*H_*S_*DK_;
    unsigned short* ctx = xb;                                    // alias (xb dead after gemm_qkv)

    cvt_all<<<(XN4 + 4*WN4)/256, 256, 0, stream>>>(x, Wq, Wk, Wv, Wo, xb, Wb, Wob);

    gemm_qkv<<<768, 512, 0, stream>>>(xb, Wb, theta, qb, kb, vtb);
    flash_attn<<<dim3(S_/256, B_*H_), 256, 0, stream>>>(qb, kb, vtb, ctx);
    gemm_out<<<256, 512, 0, stream>>>(ctx, Wob, out);
}

// Round 9
// 241.233 us; speedup vs baseline: 3.6040x; 1.0424x over previous
//
#include <hip/hip_runtime.h>

// Problem constants
#define B_  4
#define S_  2048
#define E_  1024
#define H_  16
#define DK_ 64
#define M_  (B_*S_)   // 8192

typedef __attribute__((ext_vector_type(8)))  short short8;   // 8 bf16 (4 VGPRs)
typedef __attribute__((ext_vector_type(4)))  float f32x4;
typedef __attribute__((ext_vector_type(16))) float f32x16;   // 32x32 MFMA accumulator

#define QSCALE 0.18033688f   // 0.125 * log2(e): folded into Q so p = exp2(score)

// fp32 -> bf16 round-to-nearest-even
__device__ __forceinline__ unsigned short f2b(float f) {
    union { float f; unsigned u; } v; v.f = f;
    unsigned u = v.u;
    return (unsigned short)((u + 0x7fffu + ((u >> 16) & 1u)) >> 16);
}

// async global->LDS, 16 bytes/lane. LDS dest = wave-uniform base + lane*16.
__device__ __forceinline__ void gload_lds16(const unsigned short* g, unsigned short* l) {
    __builtin_amdgcn_global_load_lds((const __attribute__((address_space(1))) void*)g,
                                     (__attribute__((address_space(3))) void*)l, 16, 0, 0);
}

// One launch for all fp32->bf16 converts: x (M*E) then Wq,Wk,Wv,Wo (E*E each).
#define XN4 (M_*E_/4)
#define WN4 (E_*E_/4)
__global__ __launch_bounds__(256) void cvt_all(
    const float* __restrict__ x,
    const float* __restrict__ w0, const float* __restrict__ w1,
    const float* __restrict__ w2, const float* __restrict__ w3,
    unsigned short* __restrict__ xb, unsigned short* __restrict__ wb,
    unsigned short* __restrict__ wob) {
    int i = blockIdx.x * 256 + threadIdx.x;
    const float* src;
    unsigned short* dst;
    int idx;
    if (i < XN4) { src = x; dst = xb; idx = i; }
    else {
        int j = i - XN4;
        int z = j >> 18;              // / WN4 (2^18)
        idx = j & (WN4 - 1);
        src = (z == 0) ? w0 : (z == 1) ? w1 : (z == 2) ? w2 : w3;
        dst = (z < 3) ? wb + (size_t)z * E_ * E_ : wob;
    }
    float4 f = ((const float4*)src)[idx];
    ushort4 o;
    o.x = f2b(f.x); o.y = f2b(f.y); o.z = f2b(f.z); o.w = f2b(f.w);
    ((ushort4*)dst)[idx] = o;
}

// ---------------------------------------------------------------------------
// 128x128-tile GEMM (r5 structure, proven best): T2 chunk-XOR swizzle;
// double-buffered LDS with stage-early (stage t+1 BEFORE compute t);
// one __syncthreads per K-tile drains vmcnt after a full compute phase.
// ---------------------------------------------------------------------------
union GemmShm {
    struct { unsigned short As0[8192], Bs0[8192], As1[8192], Bs1[8192]; } kl;  // 64 KiB
    unsigned short epi[18432];                                                  // 36 KiB epilogue scratch
};

__device__ __forceinline__ void gemm_stage(
    const unsigned short* Ag, const unsigned short* Bg,   // bases incl. k0 offset
    unsigned short* As, unsigned short* Bs, int w, int srow, int sch) {
    #pragma unroll
    for (int c = 0; c < 4; c++) {
        int ro = (w*32 + c*8 + srow);
        gload_lds16(Ag + (size_t)ro*E_ + sch, As + (w*32 + c*8)*64);
        gload_lds16(Bg + (size_t)ro*E_ + sch, Bs + (w*32 + c*8)*64);
    }
}

__device__ __forceinline__ void gemm_compute(
    const unsigned short* As, const unsigned short* Bs,
    f32x4 (&acc)[4][4], int wm, int wn, int col, int quad, int rsw) {
    #pragma unroll
    for (int kk = 0; kk < 64; kk += 32) {
        short8 a[4], b[4];
        #pragma unroll
        for (int i = 0; i < 4; i++)
            a[i] = *(const short8*)&As[(wm + i*16 + col)*64 + ((((kk>>3) + quad) ^ rsw) * 8)];
        #pragma unroll
        for (int j = 0; j < 4; j++)
            b[j] = *(const short8*)&Bs[(wn + j*16 + col)*64 + ((((kk>>3) + quad) ^ rsw) * 8)];
        __builtin_amdgcn_s_setprio(1);
        #pragma unroll
        for (int i = 0; i < 4; i++)
            #pragma unroll
            for (int j = 0; j < 4; j++)
                acc[i][j] = __builtin_amdgcn_mfma_f32_16x16x32_bf16(a[i], b[j], acc[i][j], 0, 0, 0);
        __builtin_amdgcn_s_setprio(0);
    }
}

__global__ __launch_bounds__(256) void gemm_qkv(
    const unsigned short* __restrict__ xb,   // [M][E]
    const unsigned short* __restrict__ Wb,   // [3][E][E]
    const float* __restrict__ theta,         // [64]
    unsigned short* __restrict__ qb,         // [B*H][S][DK]  (q pre-scaled)
    unsigned short* __restrict__ kb,         // [B*H][S][DK]
    unsigned short* __restrict__ vtb)        // [B*H][DK][S]
{
    __shared__ GemmShm shm;
    const int tid = threadIdx.x;
    const int w = tid >> 6, lane = tid & 63, quad = lane >> 4, col = lane & 15;
    const int wm = (w & 1) * 64, wn = (w >> 1) * 64;
    const int m0 = blockIdx.x * 128, n0 = blockIdx.y * 128, z = blockIdx.z;
    const unsigned short* Wz = Wb + (size_t)z * E_ * E_;
    const int srow = lane >> 3;
    const int sch  = ((lane & 7) ^ srow) * 8;   // pre-swizzled source chunk
    const int rsw  = col & 7;                   // read-side XOR key (row&7)

    const unsigned short* Ag = xb + (size_t)m0 * E_;
    const unsigned short* Bg = Wz + (size_t)n0 * E_;

    f32x4 acc[4][4] = {};
    gemm_stage(Ag, Bg, shm.kl.As0, shm.kl.Bs0, w, srow, sch);
    __syncthreads();
    for (int k0 = 0; k0 < E_; k0 += 128) {
        gemm_stage(Ag + k0 + 64, Bg + k0 + 64, shm.kl.As1, shm.kl.Bs1, w, srow, sch);
        gemm_compute(shm.kl.As0, shm.kl.Bs0, acc, wm, wn, col, quad, rsw);
        __syncthreads();                              // drains vmcnt: buf1 ready
        if (k0 + 128 < E_)
            gemm_stage(Ag + k0 + 128, Bg + k0 + 128, shm.kl.As0, shm.kl.Bs0, w, srow, sch);
        gemm_compute(shm.kl.As1, shm.kl.Bs1, acc, wm, wn, col, quad, rsw);
        __syncthreads();
    }

    unsigned short* ep = shm.epi;
    const int bblk = m0 >> 11;            // batch index (tile never crosses S)
    const int sbase = m0 & (S_-1);

    if (z != 2) {
        const float qs = (z == 0) ? QSCALE : 1.0f;
        // C -> ep[m][n] (stride 144), quad-XOR swizzle on n (16-elt granularity)
        #pragma unroll
        for (int j = 0; j < 4; j++) {
            int nl = wn + j*16 + col;
            float th = theta[(n0 + nl) & 63];
            #pragma unroll
            for (int i = 0; i < 4; i++)
                #pragma unroll
                for (int r = 0; r < 4; r++) {
                    int ml = wm + i*16 + quad*4 + r;
                    int nls = nl ^ (((ml >> 2) & 3) << 4);
                    ep[ml*144 + nls] = f2b(__cosf(acc[i][j][r] + th) * qs);
                }
        }
        __syncthreads();
        unsigned short* dst = (z == 0) ? qb : kb;
        const int h0 = n0 >> 6;
        #pragma unroll
        for (int k = 0; k < 8; k++) {
            int idx = k*256 + tid;
            int chunk = idx & 7, seg = idx >> 3;
            int ml = seg >> 1, hh = seg & 1;
            int ch = chunk ^ (((ml >> 2) & 3) << 1);     // de-swizzle (8-elt chunks)
            int4 val = *(const int4*)&ep[ml*144 + hh*64 + ch*8];
            size_t g = ((size_t)(bblk*H_ + h0 + hh)*S_ + sbase + ml)*DK_ + chunk*8;
            *(int4*)&dst[g] = val;
        }
    } else {
        // V: transpose tile (n-major) -> vtb[bh][d][s] coalesced rows
        #pragma unroll
        for (int j = 0; j < 4; j++) {
            int nl = wn + j*16 + col;
            float th = theta[(n0 + nl) & 63];
            #pragma unroll
            for (int i = 0; i < 4; i++)
                #pragma unroll
                for (int r = 0; r < 4; r++)
                    ep[nl*136 + wm + i*16 + quad*4 + r] = f2b(__cosf(acc[i][j][r] + th));
        }
        __syncthreads();
        int row = tid >> 1, halfm = (tid & 1) * 64;     // 2 threads per n-row
        int n = n0 + row, h = n >> 6, d = n & 63;
        size_t base = ((size_t)(bblk*H_ + h)*DK_ + d)*S_ + sbase + halfm;
        #pragma unroll
        for (int k = 0; k < 8; k++)
            *(int4*)&vtb[base + k*8] = *(const int4*)&ep[row*136 + halfm + k*8];
    }
}

// out = ctx @ Wo.T, fp32 output (same pipelined K-loop)
__global__ __launch_bounds__(256) void gemm_out(
    const unsigned short* __restrict__ ctx,  // [M][E]
    const unsigned short* __restrict__ Wob,  // [E][E]
    float* __restrict__ out)                 // [M][E] fp32
{
    __shared__ GemmShm shm;
    const int tid = threadIdx.x;
    const int w = tid >> 6, lane = tid & 63, quad = lane >> 4, col = lane & 15;
    const int wm = (w & 1) * 64, wn = (w >> 1) * 64;
    const int m0 = blockIdx.x * 128, n0 = blockIdx.y * 128;
    const int srow = lane >> 3;
    const int sch  = ((lane & 7) ^ srow) * 8;
    const int rsw  = col & 7;

    const unsigned short* Ag = ctx + (size_t)m0 * E_;
    const unsigned short* Bg = Wob + (size_t)n0 * E_;

    f32x4 acc[4][4] = {};
    gemm_stage(Ag, Bg, shm.kl.As0, shm.kl.Bs0, w, srow, sch);
    __syncthreads();
    for (int k0 = 0; k0 < E_; k0 += 128) {
        gemm_stage(Ag + k0 + 64, Bg + k0 + 64, shm.kl.As1, shm.kl.Bs1, w, srow, sch);
        gemm_compute(shm.kl.As0, shm.kl.Bs0, acc, wm, wn, col, quad, rsw);
        __syncthreads();
        if (k0 + 128 < E_)
            gemm_stage(Ag + k0 + 128, Bg + k0 + 128, shm.kl.As0, shm.kl.Bs0, w, srow, sch);
        gemm_compute(shm.kl.As1, shm.kl.Bs1, acc, wm, wn, col, quad, rsw);
        __syncthreads();
    }
    #pragma unroll
    for (int j = 0; j < 4; j++) {
        int n = n0 + wn + j*16 + col;
        #pragma unroll
        for (int i = 0; i < 4; i++)
            #pragma unroll
            for (int r = 0; r < 4; r++) {
                int m = m0 + wm + i*16 + quad*4 + r;
                out[(size_t)m*E_ + n] = acc[i][j][r];
            }
    }
}

// ---------------------------------------------------------------------------
// Flash attention, round-12: 512 threads / 8 q-group waves per block.
// Per-wave code identical to r8 (2 q-sets, KVB=128, async-STAGE dbuf,
// permlane32_swap, setprio); block now covers 512 q-rows so the same
// 71.7 KB LDS serves 8 waves -> 2 blocks/CU = 16 waves/CU = 4 waves/SIMD
// (was 2/SIMD), doubling TLP to hide the QK->exp2->PV chain.
// Staging per unit work halves. NO launch_bounds min-wave cap (r7 spill).
// ---------------------------------------------------------------------------
#define LPK 72    // Kt row stride (64 d + 8 pad)
#define LPV 136   // Vt row stride (128 keys + 8 pad)
#define KVB 128   // keys per stage

__global__ __launch_bounds__(512, 2) void flash_attn(
    const unsigned short* __restrict__ qb,   // pre-scaled by QSCALE
    const unsigned short* __restrict__ kb,
    const unsigned short* __restrict__ vtb,
    unsigned short* __restrict__ ctx)        // [M][E] bf16
{
    __shared__ unsigned short Kt[2][KVB*LPK];   // [buf][key][d]   36864 B
    __shared__ unsigned short Vt[2][64*LPV];    // [buf][d][key]   34816 B
    const int tid = threadIdx.x;
    const int w = tid >> 6, lane = tid & 63, col = lane & 31, half = lane >> 5;

    // 256 blocks = 4 q-tiles x 64 heads. f%8 = XCD; XCD x gets heads [8x,8x+8).
    const int f   = blockIdx.y * gridDim.x + blockIdx.x;   // 0..255
    const int swz = (f & 7) * 32 + (f >> 3);               // bijective (256 = 8*32)
    const int q0  = (swz & 3) * 512;
    const int bh  = swz >> 2;

    const unsigned short* kbase = kb  + (size_t)bh * S_ * DK_;
    const unsigned short* vbase = vtb + (size_t)bh * DK_ * S_;

    // Two Q fragment sets: rows q0 + w*64 + s*32 + col
    short8 qf[2][4];
    {
        const unsigned short* qrow = qb + ((size_t)bh*S_ + q0 + w*64 + col)*DK_;
        #pragma unroll
        for (int s = 0; s < 2; s++)
            #pragma unroll
            for (int c = 0; c < 4; c++)
                qf[s][c] = *(const short8*)&qrow[(size_t)s*32*DK_ + c*16 + half*8];
    }

    union U8 { unsigned u[4]; short8 s8; };
    U8 ones;
    #pragma unroll
    for (int i = 0; i < 4; i++) ones.u[i] = 0x3F803F80u;   // bf16 1.0 pair

    f32x16 oacc[2][2] = {};   // [set][dt]
    f32x16 lacc[2] = {};      // [set]

    // prologue: stage tile 0 into buf 0 (K: 128x64, V: 64x128), 512 threads
    #pragma unroll
    for (int j = 0; j < 2; j++) {
        int s = tid + j*512;
        int krow = s >> 3, kc8 = (s & 7) * 8;
        int vrow = s >> 4, vc8 = (s & 15) * 8;
        *(int4*)&Kt[0][krow*LPK + kc8] = *(const int4*)&kbase[(size_t)krow*DK_ + kc8];
        *(int4*)&Vt[0][vrow*LPV + vc8] = *(const int4*)&vbase[(size_t)vrow*S_ + vc8];
    }
    __syncthreads();

    for (int it = 0; it < S_/KVB; ++it) {
        const int cur = it & 1, nxt = cur ^ 1;
        const int ktn = it*KVB + KVB;
        int4 rk[2], rv[2];
        if (ktn < S_) {                      // issue next-tile loads EARLY
            #pragma unroll
            for (int j = 0; j < 2; j++) {
                int s = tid + j*512;
                int krow = s >> 3, kc8 = (s & 7) * 8;
                int vrow = s >> 4, vc8 = (s & 15) * 8;
                rk[j] = *(const int4*)&kbase[(size_t)(ktn + krow)*DK_ + kc8];
                rv[j] = *(const int4*)&vbase[(size_t)vrow*S_ + ktn + vc8];
            }
        }

        #pragma unroll
        for (int t = 0; t < 4; t++) {
            // S^T = K.Q^T over this 32-key subtile, both q-sets share kf
            f32x16 sa0 = {}, sa1 = {};
            __builtin_amdgcn_s_setprio(1);
            #pragma unroll
            for (int c = 0; c < 4; c++) {
                short8 kf = *(const short8*)&Kt[cur][(t*32 + col)*LPK + c*16 + half*8];
                sa0 = __builtin_amdgcn_mfma_f32_32x32x16_bf16(kf, qf[0][c], sa0, 0, 0, 0);
                sa1 = __builtin_amdgcn_mfma_f32_32x32x16_bf16(kf, qf[1][c], sa1, 0, 0, 0);
            }
            __builtin_amdgcn_s_setprio(0);
            // p = exp2(score); pack pairs via v_perm (hi-16 truncation)
            unsigned pk[2][4][2];
            #pragma unroll
            for (int rg = 0; rg < 4; rg++) {
                float a0 = __builtin_amdgcn_exp2f(sa0[rg*4+0]);
                float a1 = __builtin_amdgcn_exp2f(sa0[rg*4+1]);
                float a2 = __builtin_amdgcn_exp2f(sa0[rg*4+2]);
                float a3 = __builtin_amdgcn_exp2f(sa0[rg*4+3]);
                pk[0][rg][0] = __builtin_amdgcn_perm(__float_as_uint(a1), __float_as_uint(a0), 0x07060302u);
                pk[0][rg][1] = __builtin_amdgcn_perm(__float_as_uint(a3), __float_as_uint(a2), 0x07060302u);
                float b0 = __builtin_amdgcn_exp2f(sa1[rg*4+0]);
                float b1 = __builtin_amdgcn_exp2f(sa1[rg*4+1]);
                float b2 = __builtin_amdgcn_exp2f(sa1[rg*4+2]);
                float b3 = __builtin_amdgcn_exp2f(sa1[rg*4+3]);
                pk[1][rg][0] = __builtin_amdgcn_perm(__float_as_uint(b1), __float_as_uint(b0), 0x07060302u);
                pk[1][rg][1] = __builtin_amdgcn_perm(__float_as_uint(b3), __float_as_uint(b2), 0x07060302u);
            }
            // PV + l over the two 16-key chunks; vf shared across q-sets
            #pragma unroll
            for (int kc = 0; kc < 2; kc++) {
                const int lo = 2*kc, hi = 2*kc + 1;
                U8 pa[2];
                #pragma unroll
                for (int s = 0; s < 2; s++) {
                    auto s0 = __builtin_amdgcn_permlane32_swap((int)pk[s][lo][0], (int)pk[s][hi][0], false, false);
                    auto s1 = __builtin_amdgcn_permlane32_swap((int)pk[s][lo][1], (int)pk[s][hi][1], false, false);
                    pa[s].u[0] = (unsigned)s0[0];
                    pa[s].u[1] = (unsigned)s1[0];
                    pa[s].u[2] = (unsigned)s0[1];
                    pa[s].u[3] = (unsigned)s1[1];
                }
                __builtin_amdgcn_s_setprio(1);
                lacc[0] = __builtin_amdgcn_mfma_f32_32x32x16_bf16(pa[0].s8, ones.s8, lacc[0], 0, 0, 0);
                lacc[1] = __builtin_amdgcn_mfma_f32_32x32x16_bf16(pa[1].s8, ones.s8, lacc[1], 0, 0, 0);
                #pragma unroll
                for (int dt = 0; dt < 2; dt++) {
                    short8 vf = *(const short8*)&Vt[cur][(dt*32 + col)*LPV + t*32 + kc*16 + half*8];
                    oacc[0][dt] = __builtin_amdgcn_mfma_f32_32x32x16_bf16(pa[0].s8, vf, oacc[0][dt], 0, 0, 0);
                    oacc[1][dt] = __builtin_amdgcn_mfma_f32_32x32x16_bf16(pa[1].s8, vf, oacc[1][dt], 0, 0, 0);
                }
                __builtin_amdgcn_s_setprio(0);
            }
        }

        if (ktn < S_) {                      // write next tile LATE (vmcnt here)
            #pragma unroll
            for (int j = 0; j < 2; j++) {
                int s = tid + j*512;
                int krow = s >> 3, kc8 = (s & 7) * 8;
                int vrow = s >> 4, vc8 = (s & 15) * 8;
                *(int4*)&Kt[nxt][krow*LPK + kc8] = rk[j];
                *(int4*)&Vt[nxt][vrow*LPV + vc8] = rv[j];
            }
        }
        __syncthreads();
    }

    // epilogue: lacc rows match oacc rows exactly (C row = rr + 8*rg + 4*half)
    const int b = bh >> 4, h = bh & 15;
    #pragma unroll
    for (int s = 0; s < 2; s++)
        #pragma unroll
        for (int rg = 0; rg < 4; rg++)
            #pragma unroll
            for (int rr = 0; rr < 4; rr++) {
                int row = rr + rg*8 + half*4;
                float inv = 1.0f / lacc[s][rg*4 + rr];
                int sq = q0 + w*64 + s*32 + row;
                size_t rowoff = ((size_t)(b*S_ + sq))*E_ + h*64;
                #pragma unroll
                for (int dt = 0; dt < 2; dt++)
                    ctx[rowoff + dt*32 + col] = f2b(oacc[s][dt][rg*4 + rr] * inv);
            }
}

extern "C" void kernel_launch(void* const* d_in, const int* in_sizes, int n_in,
                              void* d_out, int out_size, void* d_ws, size_t ws_size,
                              hipStream_t stream) {
    (void)in_sizes; (void)n_in; (void)out_size; (void)ws_size;
    const float* x     = (const float*)d_in[0];
    const float* Wq    = (const float*)d_in[1];
    const float* Wk    = (const float*)d_in[2];
    const float* Wv    = (const float*)d_in[3];
    const float* Wo    = (const float*)d_in[4];
    const float* theta = (const float*)d_in[5];
    float* out = (float*)d_out;

    unsigned short* ws  = (unsigned short*)d_ws;
    unsigned short* xb  = ws;                                    // M*E
    unsigned short* Wb  = xb  + (size_t)M_*E_;                   // 3*E*E
    unsigned short* Wob = Wb  + (size_t)3*E_*E_;                 // E*E
    unsigned short* qb  = Wob + (size_t)E_*E_;
    unsigned short* kb  = qb  + (size_t)B_*H_*S_*DK_;
    unsigned short* vtb = kb  + (size_t)B_*H_*S_*DK_;
    unsigned short* ctx = xb;                                    // alias (xb dead after gemm_qkv)

    cvt_all<<<(XN4 + 4*WN4)/256, 256, 0, stream>>>(x, Wq, Wk, Wv, Wo, xb, Wb, Wob);

    gemm_qkv<<<dim3(M_/128, E_/128, 3), 256, 0, stream>>>(xb, Wb, theta, qb, kb, vtb);
    flash_attn<<<dim3(S_/512, B_*H_), 512, 0, stream>>>(qb, kb, vtb, ctx);
    gemm_out<<<dim3(M_/128, E_/128), 256, 0, stream>>>(ctx, Wob, out);
}